// Round 4
// baseline (1209.663 us; speedup 1.0000x reference)
//
#include <hip/hip_runtime.h>
#include <stdint.h>

typedef uint32_t u32;
typedef float f32x4 __attribute__((ext_vector_type(4)));
typedef u32 u32x4 __attribute__((ext_vector_type(4)));
typedef short s16x8 __attribute__((ext_vector_type(8)));  // 8 bf16 in 4 VGPRs (guide §3)

#define DI __device__ __forceinline__

DI unsigned short f2bf(float f) {
    u32 u = __builtin_bit_cast(u32, f);
    u32 r = (u + 0x7fffu + ((u >> 16) & 1u)) >> 16;
    return (unsigned short)r;
}
DI float bf2f(unsigned short s) {
    u32 u = ((u32)s) << 16;
    return __builtin_bit_cast(float, u);
}
DI u32 pack2(unsigned short lo, unsigned short hi) { return (u32)lo | ((u32)hi << 16); }

// Builtin MFMA: compiler-known semantics -> hazard nops / waitcnts inserted
// correctly (inline-asm MFMA is NOT seen by the MAI hazard recognizer).
DI void mfma_bf16(f32x4& acc, u32x4 a, u32x4 b) {
    acc = __builtin_amdgcn_mfma_f32_16x16x32_bf16(
        __builtin_bit_cast(s16x8, a), __builtin_bit_cast(s16x8, b), acc, 0, 0, 0);
}

// ---------------- cast f32 -> bf16 (straight) ----------------
__global__ __launch_bounds__(256) void k_cast(const float* __restrict__ X,
                                              unsigned short* __restrict__ Y, int n4) {
    int i = blockIdx.x * 256 + threadIdx.x;
    if (i < n4) {
        float4 v = ((const float4*)X)[i];
        ushort4 o;
        o.x = f2bf(v.x); o.y = f2bf(v.y); o.z = f2bf(v.z); o.w = f2bf(v.w);
        ((ushort4*)Y)[i] = o;
    }
}

// ---------------- cast+transpose W[K][N] f32 -> Wt[N][K] bf16 ----------------
__global__ __launch_bounds__(256) void k_tcast(const float* __restrict__ W,
                                               unsigned short* __restrict__ Wt) {
    __shared__ float t[64][65];
    const int K = 3072;
    int k0 = blockIdx.y * 64, n0 = blockIdx.x * 64;
    int tid = threadIdx.x;
    int r = tid >> 4, c4 = (tid & 15) * 4;
#pragma unroll
    for (int i = 0; i < 4; i++) {
        float4 v = *(const float4*)(W + (size_t)(k0 + r + i * 16) * K + n0 + c4);
        t[r + i * 16][c4 + 0] = v.x;
        t[r + i * 16][c4 + 1] = v.y;
        t[r + i * 16][c4 + 2] = v.z;
        t[r + i * 16][c4 + 3] = v.w;
    }
    __syncthreads();
#pragma unroll
    for (int i = 0; i < 4; i++) {
        int n = r + i * 16;
        ushort4 o;
        o.x = f2bf(t[c4 + 0][n]);
        o.y = f2bf(t[c4 + 1][n]);
        o.z = f2bf(t[c4 + 2][n]);
        o.w = f2bf(t[c4 + 3][n]);
        *(ushort4*)(Wt + (size_t)(n0 + n) * K + k0 + c4) = o;
    }
}

// ---------------- GEMM: C[M][3072] = A[M][3072] * Bt[3072][3072]^T + bias ----------------
// epi 0: out bf16 Q/K raw  [24][2560][128], row -> s_off+m, col n -> (h=n>>7, d=n&127)
// epi 1: out bf16 V transposed [24][128][2560]
// epi 2: out f32  [M][3072]  (out-projection result)
__global__ __launch_bounds__(256) void k_gemm(const unsigned short* __restrict__ A,
                                              const unsigned short* __restrict__ Bt,
                                              const float* __restrict__ bias, void* outp,
                                              int s_off, int epi) {
    __shared__ u32x4 Al[512];  // 128 rows x 32 k  (bf16), 16B granules
    __shared__ u32x4 Bl[512];  // 128 n-rows x 32 k
    const int K = 3072;
    int tid = threadIdx.x;
    int lane = tid & 63, w = tid >> 6;
    int wr = w >> 1, wc = w & 1;
    int l15 = lane & 15, lg = lane >> 4;
    int m0 = blockIdx.y * 128, n0 = blockIdx.x * 128;

    f32x4 acc[4][4] = {};

    int r0 = tid >> 2, c0 = (tid & 3) * 8;
    const unsigned short* Ag = A + (size_t)(m0 + r0) * K + c0;
    const unsigned short* Ag2 = A + (size_t)(m0 + 64 + r0) * K + c0;
    const unsigned short* Bg = Bt + (size_t)(n0 + r0) * K + c0;
    const unsigned short* Bg2 = Bt + (size_t)(n0 + 64 + r0) * K + c0;

    for (int k0 = 0; k0 < K; k0 += 32) {
        __syncthreads();
        Al[tid] = *(const u32x4*)(Ag + k0);
        Al[tid + 256] = *(const u32x4*)(Ag2 + k0);
        Bl[tid] = *(const u32x4*)(Bg + k0);
        Bl[tid + 256] = *(const u32x4*)(Bg2 + k0);
        __syncthreads();
        u32x4 af[4], bf[4];
#pragma unroll
        for (int i = 0; i < 4; i++) {
            af[i] = Al[(wr * 64 + i * 16 + l15) * 4 + lg];
            bf[i] = Bl[(wc * 64 + i * 16 + l15) * 4 + lg];
        }
#pragma unroll
        for (int i = 0; i < 4; i++)
#pragma unroll
            for (int j = 0; j < 4; j++) mfma_bf16(acc[i][j], af[i], bf[j]);
    }

#pragma unroll
    for (int j = 0; j < 4; j++) {
        int n = n0 + wc * 64 + j * 16 + l15;
        float b = bias[n];
#pragma unroll
        for (int i = 0; i < 4; i++) {
#pragma unroll
            for (int r = 0; r < 4; r++) {
                int m = m0 + wr * 64 + i * 16 + lg * 4 + r;
                float v = acc[i][j][r] + b;
                if (epi == 2) {
                    ((float*)outp)[(size_t)m * 3072 + n] = v;
                } else {
                    int h = n >> 7, d = n & 127;
                    size_t addr = (epi == 0)
                                      ? (((size_t)h * 2560 + s_off + m) * 128 + d)
                                      : (((size_t)h * 128 + d) * 2560 + s_off + m);
                    ((unsigned short*)outp)[addr] = f2bf(v);
                }
            }
        }
    }
}

// ---------------- RMSNorm + RoPE, in-place on Q and K [24][2560][128] bf16 ----------------
__global__ __launch_bounds__(256) void k_normrope(unsigned short* __restrict__ Q,
                                                  unsigned short* __restrict__ Kb,
                                                  const float* gq, const float* gk,
                                                  const float* gaq, const float* gak,
                                                  const float* img_cos, const float* img_sin,
                                                  const float* txt_cos, const float* txt_sin) {
    int w = threadIdx.x >> 6, lane = threadIdx.x & 63;
    int s = blockIdx.x * 4 + w;  // 0..2559
    int h = blockIdx.y;          // 0..23
    int tensor = blockIdx.z;     // 0=Q 1=K
    unsigned short* base = (tensor ? Kb : Q) + ((size_t)h * 2560 + s) * 128;
    bool txt = s < 512;
    const float* g = tensor ? (txt ? gak : gk) : (txt ? gaq : gq);
    const float* ct = txt ? txt_cos + (size_t)s * 64 : img_cos + (size_t)(s - 512) * 64;
    const float* st = txt ? txt_sin + (size_t)s * 64 : img_sin + (size_t)(s - 512) * 64;

    u32 v = ((u32*)base)[lane];
    float xr = bf2f((unsigned short)(v & 0xffff));
    float xi = bf2f((unsigned short)(v >> 16));
    float ss = xr * xr + xi * xi;
#pragma unroll
    for (int m = 1; m < 64; m <<= 1) ss += __shfl_xor(ss, m);
    float rs = rsqrtf(ss * (1.0f / 128.0f) + 1e-6f);
    float c = ct[lane], sn = st[lane];
    float g0 = g[2 * lane], g1 = g[2 * lane + 1];
    xr *= rs * g0;
    xi *= rs * g1;
    float orr = xr * c - xi * sn;
    float oi = xr * sn + xi * c;
    ((u32*)base)[lane] = pack2(f2bf(orr), f2bf(oi));
}

// ---------------- flash attention ----------------
// Q,K: [24][2560][128] bf16 ; Vt: [24][128][2560] bf16 ; J out: [2560][3072] bf16
__global__ __launch_bounds__(256) void k_attn(const unsigned short* __restrict__ Q,
                                              const unsigned short* __restrict__ Kb,
                                              const unsigned short* __restrict__ Vt,
                                              unsigned short* __restrict__ J) {
    __shared__ unsigned short Kl[64 * 136];  // K tile [64 kv][128 d], row pad to 136
    __shared__ unsigned short Vl[128 * 72];  // V tile [128 d][64 kv], row pad to 72
    int tid = threadIdx.x;
    int lane = tid & 63, w = tid >> 6;
    int l15 = lane & 15, lg = lane >> 4;
    int h = blockIdx.y, qb = blockIdx.x;
    int q0 = qb * 64 + w * 16;
    const float scale = 0.08838834764831845f;

    u32x4 qf[4];
    const unsigned short* qrow = Q + ((size_t)h * 2560 + q0 + l15) * 128;
#pragma unroll
    for (int c = 0; c < 4; c++) qf[c] = *(const u32x4*)(qrow + c * 32 + lg * 8);

    float m_run = -1e30f, l_run = 0.0f;
    f32x4 oa[8] = {};

    int tr = tid >> 4, tc8 = (tid & 15) * 8;
    const unsigned short* Kg = Kb + (size_t)h * 2560 * 128;
    int vd = tid >> 1, vs = (tid & 1) * 32;
    const unsigned short* Vg = Vt + ((size_t)h * 128 + vd) * 2560 + vs;

    for (int kt = 0; kt < 40; kt++) {
        __syncthreads();
#pragma unroll
        for (int i = 0; i < 4; i++) {
            int row = tr + i * 16;
            *(u32x4*)&Kl[row * 136 + tc8] =
                *(const u32x4*)(Kg + (size_t)(kt * 64 + row) * 128 + tc8);
        }
#pragma unroll
        for (int j = 0; j < 4; j++)
            *(u32x4*)&Vl[vd * 72 + vs + j * 8] = *(const u32x4*)(Vg + kt * 64 + j * 8);
        __syncthreads();

        // S = K * Q^T  (swapped): lane owns q-col l15, k-rows lg*4+r (+16*ks)
        f32x4 sc[4] = {};
#pragma unroll
        for (int ks = 0; ks < 4; ks++)
#pragma unroll
            for (int c = 0; c < 4; c++) {
                u32x4 kf = *(u32x4*)&Kl[(ks * 16 + l15) * 136 + c * 32 + lg * 8];
                mfma_bf16(sc[ks], kf, qf[c]);
            }

        float ps[16];
        float tmax = -1e30f;
#pragma unroll
        for (int ks = 0; ks < 4; ks++)
#pragma unroll
            for (int r = 0; r < 4; r++) {
                float sv = sc[ks][r] * scale;
                ps[ks * 4 + r] = sv;
                tmax = fmaxf(tmax, sv);
            }
        tmax = fmaxf(tmax, __shfl_xor(tmax, 16));
        tmax = fmaxf(tmax, __shfl_xor(tmax, 32));
        float m_new = fmaxf(m_run, tmax);
        float fsc = __expf(m_run - m_new);
        float lsum = 0.0f;
#pragma unroll
        for (int t = 0; t < 16; t++) {
            ps[t] = __expf(ps[t] - m_new);
            lsum += ps[t];
        }
        lsum += __shfl_xor(lsum, 16);
        lsum += __shfl_xor(lsum, 32);
        l_run = l_run * fsc + lsum;
        m_run = m_new;
#pragma unroll
        for (int dg = 0; dg < 8; dg++) oa[dg] *= fsc;

        // pack P -> bf16 frags; slot j of chunk c holds k = 32c + 16(j>>2) + 4*lg + (j&3)
        u32x4 pb[2];
#pragma unroll
        for (int c = 0; c < 2; c++)
#pragma unroll
            for (int i = 0; i < 4; i++)
                pb[c][i] = pack2(f2bf(ps[8 * c + 2 * i]), f2bf(ps[8 * c + 2 * i + 1]));

        // O^T += V^T * P : A-frag from Vl with the same slot->k bijection
#pragma unroll
        for (int dg = 0; dg < 8; dg++) {
            int d = dg * 16 + l15;
#pragma unroll
            for (int c = 0; c < 2; c++) {
                uint2 lo = *(uint2*)&Vl[d * 72 + 32 * c + 4 * lg];
                uint2 hi = *(uint2*)&Vl[d * 72 + 32 * c + 16 + 4 * lg];
                u32x4 vf;
                vf[0] = lo.x; vf[1] = lo.y; vf[2] = hi.x; vf[3] = hi.y;
                mfma_bf16(oa[dg], vf, pb[c]);
            }
        }
    }

    float inv = 1.0f / l_run;
#pragma unroll
    for (int dg = 0; dg < 8; dg++)
#pragma unroll
        for (int r = 0; r < 4; r++) {
            int d = dg * 16 + lg * 4 + r;
            J[(size_t)(q0 + l15) * 3072 + h * 128 + d] = f2bf(oa[dg][r] * inv);
        }
}

extern "C" void kernel_launch(void* const* d_in, const int* in_sizes, int n_in,
                              void* d_out, int out_size, void* d_ws, size_t ws_size,
                              hipStream_t stream) {
    const float* image = (const float*)d_in[0];
    const float* text = (const float*)d_in[1];
    const float* img_cos = (const float*)d_in[2];
    const float* img_sin = (const float*)d_in[3];
    const float* txt_cos = (const float*)d_in[4];
    const float* txt_sin = (const float*)d_in[5];
    const float* Wq = (const float*)d_in[6];
    const float* bq = (const float*)d_in[7];
    const float* Wk = (const float*)d_in[8];
    const float* bk = (const float*)d_in[9];
    const float* Wv = (const float*)d_in[10];
    const float* bv = (const float*)d_in[11];
    const float* Waq = (const float*)d_in[12];
    const float* baq = (const float*)d_in[13];
    const float* Wak = (const float*)d_in[14];
    const float* bak = (const float*)d_in[15];
    const float* Wav = (const float*)d_in[16];
    const float* bav = (const float*)d_in[17];
    const float* gq = (const float*)d_in[18];
    const float* gk = (const float*)d_in[19];
    const float* gaq = (const float*)d_in[20];
    const float* gak = (const float*)d_in[21];
    const float* Wo = (const float*)d_in[22];
    const float* bo = (const float*)d_in[23];
    const float* Wao = (const float*)d_in[24];
    const float* bao = (const float*)d_in[25];

    // Workspace layout (peak 81,788,928 B):
    //   WT [0, 18874368)           weight^T bf16 (reused per GEMM)
    //   XI [18874368, 31457280)    image bf16        \ dead after QKV gemms;
    //   XT [31457280, 34603008)    text bf16         / J aliases this 15.7MB
    //   Qb [34603008, 50331648)
    //   Kb [50331648, 66060288)
    //   VT [66060288, 81788928)
    char* ws = (char*)d_ws;
    unsigned short* WT = (unsigned short*)ws;
    unsigned short* XI = (unsigned short*)(ws + 18874368);
    unsigned short* XT = (unsigned short*)(ws + 31457280);
    unsigned short* Qb = (unsigned short*)(ws + 34603008);
    unsigned short* Kbuf = (unsigned short*)(ws + 50331648);
    unsigned short* VT = (unsigned short*)(ws + 66060288);
    unsigned short* J = XI;  // alias: XI/XT dead before k_attn writes J

    float* out_img = (float*)d_out;                  // 2048*3072
    float* out_txt = (float*)d_out + 6291456;        // 512*3072

    k_cast<<<6144, 256, 0, stream>>>(image, XI, 1572864);
    k_cast<<<1536, 256, 0, stream>>>(text, XT, 393216);

    dim3 tg(48, 48);
    dim3 gi(24, 16);  // M=2048
    dim3 gt(24, 4);   // M=512

    // image QKV
    k_tcast<<<tg, 256, 0, stream>>>(Wq, WT);
    k_gemm<<<gi, 256, 0, stream>>>(XI, WT, bq, Qb, 512, 0);
    k_tcast<<<tg, 256, 0, stream>>>(Wk, WT);
    k_gemm<<<gi, 256, 0, stream>>>(XI, WT, bk, Kbuf, 512, 0);
    k_tcast<<<tg, 256, 0, stream>>>(Wv, WT);
    k_gemm<<<gi, 256, 0, stream>>>(XI, WT, bv, VT, 512, 1);
    // text QKV
    k_tcast<<<tg, 256, 0, stream>>>(Waq, WT);
    k_gemm<<<gt, 256, 0, stream>>>(XT, WT, baq, Qb, 0, 0);
    k_tcast<<<tg, 256, 0, stream>>>(Wak, WT);
    k_gemm<<<gt, 256, 0, stream>>>(XT, WT, bak, Kbuf, 0, 0);
    k_tcast<<<tg, 256, 0, stream>>>(Wav, WT);
    k_gemm<<<gt, 256, 0, stream>>>(XT, WT, bav, VT, 0, 1);

    k_normrope<<<dim3(640, 24, 2), 256, 0, stream>>>(Qb, Kbuf, gq, gk, gaq, gak,
                                                     img_cos, img_sin, txt_cos, txt_sin);

    k_attn<<<dim3(40, 24), 256, 0, stream>>>(Qb, Kbuf, VT, J);

    // output projections
    k_tcast<<<tg, 256, 0, stream>>>(Wao, WT);
    k_gemm<<<gt, 256, 0, stream>>>(J, WT, bao, out_txt, 0, 2);
    k_tcast<<<tg, 256, 0, stream>>>(Wo, WT);
    k_gemm<<<gi, 256, 0, stream>>>(J + (size_t)512 * 3072, WT, bo, out_img, 0, 2);
}

// Round 6
// 1097.717 us; speedup vs baseline: 1.1020x; 1.1020x over previous
//
#include <hip/hip_runtime.h>
#include <stdint.h>

typedef uint32_t u32;
typedef float f32x4 __attribute__((ext_vector_type(4)));
typedef u32 u32x4 __attribute__((ext_vector_type(4)));
typedef short s16x8 __attribute__((ext_vector_type(8)));

#define DI __device__ __forceinline__

DI unsigned short f2bf(float f) {
    u32 u = __builtin_bit_cast(u32, f);
    u32 r = (u + 0x7fffu + ((u >> 16) & 1u)) >> 16;
    return (unsigned short)r;
}
DI float bf2f(unsigned short s) {
    u32 u = ((u32)s) << 16;
    return __builtin_bit_cast(float, u);
}
DI u32 pack2(unsigned short lo, unsigned short hi) { return (u32)lo | ((u32)hi << 16); }

DI void mfma_bf16(f32x4& acc, u32x4 a, u32x4 b) {
    acc = __builtin_amdgcn_mfma_f32_16x16x32_bf16(
        __builtin_bit_cast(s16x8, a), __builtin_bit_cast(s16x8, b), acc, 0, 0, 0);
}

// async global->LDS, 16B per lane; LDS dest = wave-uniform base + lane*16.
// AS1 cast via inttoptr (bit-identical); AS3 via low-32 truncation (generic LDS
// pointers carry the group offset in the low 32 bits on amdgcn).
DI void gload16(const unsigned short* g, unsigned short* l) {
    __builtin_amdgcn_global_load_lds(
        (const __attribute__((address_space(1))) uint32_t*)(uintptr_t)g,
        (__attribute__((address_space(3))) uint32_t*)(uint32_t)(uintptr_t)l, 16, 0, 0);
}

// ---------------- cast f32 -> bf16 ----------------
__global__ __launch_bounds__(256) void k_cast(const float* __restrict__ X,
                                              unsigned short* __restrict__ Y, int n4) {
    int i = blockIdx.x * 256 + threadIdx.x;
    if (i < n4) {
        float4 v = ((const float4*)X)[i];
        ushort4 o;
        o.x = f2bf(v.x); o.y = f2bf(v.y); o.z = f2bf(v.z); o.w = f2bf(v.w);
        ((ushort4*)Y)[i] = o;
    }
}

// ---------------- cast+transpose W[K][N] f32 -> Wt[N][K] bf16 ----------------
__global__ __launch_bounds__(256) void k_tcast(const float* __restrict__ W,
                                               unsigned short* __restrict__ Wt) {
    __shared__ float t[64][65];
    const int K = 3072;
    int k0 = blockIdx.y * 64, n0 = blockIdx.x * 64;
    int tid = threadIdx.x;
    int r = tid >> 4, c4 = (tid & 15) * 4;
#pragma unroll
    for (int i = 0; i < 4; i++) {
        float4 v = *(const float4*)(W + (size_t)(k0 + r + i * 16) * K + n0 + c4);
        t[r + i * 16][c4 + 0] = v.x;
        t[r + i * 16][c4 + 1] = v.y;
        t[r + i * 16][c4 + 2] = v.z;
        t[r + i * 16][c4 + 3] = v.w;
    }
    __syncthreads();
#pragma unroll
    for (int i = 0; i < 4; i++) {
        int n = r + i * 16;
        ushort4 o;
        o.x = f2bf(t[c4 + 0][n]);
        o.y = f2bf(t[c4 + 1][n]);
        o.z = f2bf(t[c4 + 2][n]);
        o.w = f2bf(t[c4 + 3][n]);
        *(ushort4*)(Wt + (size_t)(n0 + n) * K + k0 + c4) = o;
    }
}

// ---------------- GEMM: C[M][3072] = A[M][3072] * Bt^T + bias ----------------
// global_load_lds staging, 2-buffer 2-phase pipeline, granule-swizzled LDS.
// epi 0: out bf16 [24][2560][128] at row s_off+m, (h,d) = (n>>7, n&127)
// epi 2: out f32  [M][3072]
__global__ __launch_bounds__(256) void k_gemm(const unsigned short* __restrict__ A,
                                              const unsigned short* __restrict__ Bt,
                                              const float* __restrict__ bias, void* outp,
                                              int s_off, int epi) {
    __shared__ unsigned short Al[2][4096];  // [128 rows][32 k] linear, 8KB per buf
    __shared__ unsigned short Bl[2][4096];
    const int K = 3072;
    int tid = threadIdx.x;
    int lane = tid & 63, w = tid >> 6;
    int wr = w >> 1, wc = w & 1;
    int l15 = lane & 15, lg = lane >> 4;
    int m0 = blockIdx.y * 128, n0 = blockIdx.x * 128;

    f32x4 acc[4][4] = {};

    // wave w stages rows [w*32, w*32+32) of A and B (2 issues x 16 rows x 64B).
    // lane: row = w*32 + i*16 + (lane>>2); LDS slot lane&3 receives global
    // granule (lane&3)^((row>>1)&3)  [bank swizzle, rule #21: swizzle the source]
    int srow = w * 32 + (lane >> 2);
    int colsw = ((lane & 3) ^ ((lane >> 3) & 3)) * 8;
    const unsigned short* Ag = A + (size_t)(m0 + srow) * K + colsw;
    const unsigned short* Bg = Bt + (size_t)(n0 + srow) * K + colsw;
    int gsw = (l15 >> 1) & 3;  // read-side granule swizzle (= (row>>1)&3 for frag rows)

#pragma unroll
    for (int i = 0; i < 2; i++) {
        gload16(Ag + (size_t)i * 16 * K, &Al[0][w * 1024 + i * 512]);
        gload16(Bg + (size_t)i * 16 * K, &Bl[0][w * 1024 + i * 512]);
    }
    __syncthreads();  // implicit vmcnt(0) drain before barrier

    int cur = 0;
    for (int k0 = 0; k0 < K; k0 += 32) {
        if (k0 + 32 < K) {
#pragma unroll
            for (int i = 0; i < 2; i++) {
                gload16(Ag + (size_t)i * 16 * K + k0 + 32, &Al[cur ^ 1][w * 1024 + i * 512]);
                gload16(Bg + (size_t)i * 16 * K + k0 + 32, &Bl[cur ^ 1][w * 1024 + i * 512]);
            }
        }
        u32x4 af[4], bf[4];
#pragma unroll
        for (int i = 0; i < 4; i++) {
            int ar = wr * 64 + i * 16 + l15;
            int br = wc * 64 + i * 16 + l15;
            af[i] = *(const u32x4*)&Al[cur][ar * 32 + (lg ^ gsw) * 8];
            bf[i] = *(const u32x4*)&Bl[cur][br * 32 + (lg ^ gsw) * 8];
        }
#pragma unroll
        for (int i = 0; i < 4; i++)
#pragma unroll
            for (int j = 0; j < 4; j++) mfma_bf16(acc[i][j], af[i], bf[j]);
        __syncthreads();
        cur ^= 1;
    }

#pragma unroll
    for (int j = 0; j < 4; j++) {
        int n = n0 + wc * 64 + j * 16 + l15;
        float b = bias[n];
#pragma unroll
        for (int i = 0; i < 4; i++) {
#pragma unroll
            for (int r = 0; r < 4; r++) {
                int m = m0 + wr * 64 + i * 16 + lg * 4 + r;
                float v = acc[i][j][r] + b;
                if (epi == 2) {
                    ((float*)outp)[(size_t)m * 3072 + n] = v;
                } else {
                    int h = n >> 7, d = n & 127;
                    ((unsigned short*)outp)[((size_t)h * 2560 + s_off + m) * 128 + d] = f2bf(v);
                }
            }
        }
    }
}

// ---------------- V transpose: [24][2560][128] -> [24][128][2560] ----------------
__global__ __launch_bounds__(256) void k_vtrans(const unsigned short* __restrict__ Vr,
                                                unsigned short* __restrict__ Vt) {
    __shared__ unsigned short t[64][72];
    int h = blockIdx.z, s0 = blockIdx.x * 64, d0 = blockIdx.y * 64;
    int tid = threadIdx.x;
    int r = tid >> 3, c8 = (tid & 7) * 8;
#pragma unroll
    for (int i = 0; i < 2; i++) {
        int row = r + i * 32;
        *(u32x4*)&t[row][c8] =
            *(const u32x4*)(Vr + ((size_t)h * 2560 + s0 + row) * 128 + d0 + c8);
    }
    __syncthreads();
#pragma unroll
    for (int i = 0; i < 2; i++) {
        int dr = r + i * 32;
        unsigned short tmp[8];
#pragma unroll
        for (int j = 0; j < 8; j++) tmp[j] = t[c8 + j][dr];
        *(u32x4*)(Vt + ((size_t)h * 128 + d0 + dr) * 2560 + s0 + c8) = *(u32x4*)tmp;
    }
}

// ---------------- RMSNorm + RoPE, in-place on Q and K ----------------
__global__ __launch_bounds__(256) void k_normrope(unsigned short* __restrict__ Q,
                                                  unsigned short* __restrict__ Kb,
                                                  const float* gq, const float* gk,
                                                  const float* gaq, const float* gak,
                                                  const float* img_cos, const float* img_sin,
                                                  const float* txt_cos, const float* txt_sin) {
    int w = threadIdx.x >> 6, lane = threadIdx.x & 63;
    int s = blockIdx.x * 4 + w;
    int h = blockIdx.y;
    int tensor = blockIdx.z;
    unsigned short* base = (tensor ? Kb : Q) + ((size_t)h * 2560 + s) * 128;
    bool txt = s < 512;
    const float* g = tensor ? (txt ? gak : gk) : (txt ? gaq : gq);
    const float* ct = txt ? txt_cos + (size_t)s * 64 : img_cos + (size_t)(s - 512) * 64;
    const float* st = txt ? txt_sin + (size_t)s * 64 : img_sin + (size_t)(s - 512) * 64;

    u32 v = ((u32*)base)[lane];
    float xr = bf2f((unsigned short)(v & 0xffff));
    float xi = bf2f((unsigned short)(v >> 16));
    float ss = xr * xr + xi * xi;
#pragma unroll
    for (int m = 1; m < 64; m <<= 1) ss += __shfl_xor(ss, m);
    float rs = rsqrtf(ss * (1.0f / 128.0f) + 1e-6f);
    float c = ct[lane], sn = st[lane];
    float g0 = g[2 * lane], g1 = g[2 * lane + 1];
    xr *= rs * g0;
    xi *= rs * g1;
    float orr = xr * c - xi * sn;
    float oi = xr * sn + xi * c;
    ((u32*)base)[lane] = pack2(f2bf(orr), f2bf(oi));
}

// ---------------- flash attention ----------------
// Kl: [64][128] linear, 16B-granule XOR swizzle g^(row&7) (T2; reads 2-way=free)
// Vl: [128][64] linear, granule XOR swizzle g^(d&7)
__global__ __launch_bounds__(256) void k_attn(const unsigned short* __restrict__ Q,
                                              const unsigned short* __restrict__ Kb,
                                              const unsigned short* __restrict__ Vt,
                                              unsigned short* __restrict__ J) {
    __shared__ unsigned short Kl[64 * 128];
    __shared__ unsigned short Vl[128 * 64];
    int tid = threadIdx.x;
    int lane = tid & 63, w = tid >> 6;
    int l15 = lane & 15, lg = lane >> 4;
    int h = blockIdx.y, qb = blockIdx.x;
    int q0 = qb * 64 + w * 16;
    const float scale = 0.08838834764831845f;

    u32x4 qf[4];
    const unsigned short* qrow = Q + ((size_t)h * 2560 + q0 + l15) * 128;
#pragma unroll
    for (int c = 0; c < 4; c++) qf[c] = *(const u32x4*)(qrow + c * 32 + lg * 8);

    float m_run = -1e30f, l_run = 0.0f;
    f32x4 oa[8] = {};

    int tr = tid >> 4, tg16 = tid & 15;  // K stage: row tr+16i, granule tg16
    const unsigned short* Kg = Kb + (size_t)h * 2560 * 128;
    int vd = tid >> 1, vs = (tid & 1) * 32;
    const unsigned short* Vg = Vt + ((size_t)h * 128 + vd) * 2560 + vs;
    int dsw = l15 & 7;

    for (int kt = 0; kt < 40; kt++) {
        __syncthreads();
#pragma unroll
        for (int i = 0; i < 4; i++) {
            int row = tr + i * 16;
            ((u32x4*)Kl)[row * 16 + (tg16 ^ (row & 7))] =
                *(const u32x4*)(Kg + (size_t)(kt * 64 + row) * 128 + tg16 * 8);
        }
#pragma unroll
        for (int j = 0; j < 4; j++)
            ((u32x4*)Vl)[vd * 8 + (((tid & 1) * 4 + j) ^ (vd & 7))] =
                *(const u32x4*)(Vg + kt * 64 + j * 8);
        __syncthreads();

        // S = K * Q^T (swapped): lane owns q-col l15, k-rows 4lg+r (+16ks)
        f32x4 sc[4] = {};
#pragma unroll
        for (int ks = 0; ks < 4; ks++)
#pragma unroll
            for (int c = 0; c < 4; c++) {
                int row = ks * 16 + l15;
                u32x4 kf = ((const u32x4*)Kl)[row * 16 + ((4 * c + lg) ^ (l15 & 7))];
                mfma_bf16(sc[ks], kf, qf[c]);
            }

        float ps[16];
        float tmax = -1e30f;
#pragma unroll
        for (int ks = 0; ks < 4; ks++)
#pragma unroll
            for (int r = 0; r < 4; r++) {
                float sv = sc[ks][r] * scale;
                ps[ks * 4 + r] = sv;
                tmax = fmaxf(tmax, sv);
            }
        tmax = fmaxf(tmax, __shfl_xor(tmax, 16));
        tmax = fmaxf(tmax, __shfl_xor(tmax, 32));
        float m_new = fmaxf(m_run, tmax);
        float fsc = __expf(m_run - m_new);
        float lsum = 0.0f;
#pragma unroll
        for (int t = 0; t < 16; t++) {
            ps[t] = __expf(ps[t] - m_new);
            lsum += ps[t];
        }
        lsum += __shfl_xor(lsum, 16);
        lsum += __shfl_xor(lsum, 32);
        l_run = l_run * fsc + lsum;
        m_run = m_new;
#pragma unroll
        for (int dg = 0; dg < 8; dg++) oa[dg] *= fsc;

        // pack P -> bf16; slot j of chunk c holds kv = 32c + 16(j>>2) + 4lg + (j&3)
        u32x4 pb[2];
#pragma unroll
        for (int c = 0; c < 2; c++)
#pragma unroll
            for (int i = 0; i < 4; i++)
                pb[c][i] = pack2(f2bf(ps[8 * c + 2 * i]), f2bf(ps[8 * c + 2 * i + 1]));

        // O^T += V^T * P, same slot->kv bijection for the A-frag
#pragma unroll
        for (int dg = 0; dg < 8; dg++) {
            int d = dg * 16 + l15;
            const char* vrow = (const char*)Vl + d * 128;
#pragma unroll
            for (int c = 0; c < 2; c++) {
                // lo: kv 32c+4lg (granule 4c+(lg>>1), 8B half lg&1); hi: +16 kv
                uint2 lo = *(const uint2*)(vrow +
                    (((4 * c + (lg >> 1)) ^ dsw) * 16 + (lg & 1) * 8));
                uint2 hi = *(const uint2*)(vrow +
                    (((4 * c + 2 + (lg >> 1)) ^ dsw) * 16 + (lg & 1) * 8));
                u32x4 vf;
                vf[0] = lo.x; vf[1] = lo.y; vf[2] = hi.x; vf[3] = hi.y;
                mfma_bf16(oa[dg], vf, pb[c]);
            }
        }
    }

    float inv = 1.0f / l_run;
#pragma unroll
    for (int dg = 0; dg < 8; dg++)
#pragma unroll
        for (int r = 0; r < 4; r++) {
            int d = dg * 16 + lg * 4 + r;
            J[(size_t)(q0 + l15) * 3072 + h * 128 + d] = f2bf(oa[dg][r] * inv);
        }
}

extern "C" void kernel_launch(void* const* d_in, const int* in_sizes, int n_in,
                              void* d_out, int out_size, void* d_ws, size_t ws_size,
                              hipStream_t stream) {
    const float* image = (const float*)d_in[0];
    const float* text = (const float*)d_in[1];
    const float* img_cos = (const float*)d_in[2];
    const float* img_sin = (const float*)d_in[3];
    const float* txt_cos = (const float*)d_in[4];
    const float* txt_sin = (const float*)d_in[5];
    const float* Wq = (const float*)d_in[6];
    const float* bq = (const float*)d_in[7];
    const float* Wk = (const float*)d_in[8];
    const float* bk = (const float*)d_in[9];
    const float* Wv = (const float*)d_in[10];
    const float* bv = (const float*)d_in[11];
    const float* Waq = (const float*)d_in[12];
    const float* baq = (const float*)d_in[13];
    const float* Wak = (const float*)d_in[14];
    const float* bak = (const float*)d_in[15];
    const float* Wav = (const float*)d_in[16];
    const float* bav = (const float*)d_in[17];
    const float* gq = (const float*)d_in[18];
    const float* gk = (const float*)d_in[19];
    const float* gaq = (const float*)d_in[20];
    const float* gak = (const float*)d_in[21];
    const float* Wo = (const float*)d_in[22];
    const float* bo = (const float*)d_in[23];
    const float* Wao = (const float*)d_in[24];
    const float* bao = (const float*)d_in[25];

    // Workspace (peak 81,788,928 B, same as proven-working R4 layout):
    //   WT  [0, 18874368)          weight^T bf16 (reused per GEMM)
    //   XI  [18874368, 31457280)   image bf16;  later J (J spans XI+XT = 15.7MB)
    //   XT  [31457280, 34603008)   text bf16
    //   B1  [34603008, 50331648)   Vrow first (until vtrans), then Qb
    //   Kb  [50331648, 66060288)
    //   VT  [66060288, 81788928)
    char* ws = (char*)d_ws;
    unsigned short* WT = (unsigned short*)ws;
    unsigned short* XI = (unsigned short*)(ws + 18874368);
    unsigned short* XT = (unsigned short*)(ws + 31457280);
    unsigned short* B1 = (unsigned short*)(ws + 34603008);
    unsigned short* Kbuf = (unsigned short*)(ws + 50331648);
    unsigned short* VT = (unsigned short*)(ws + 66060288);
    unsigned short* Vrow = B1;  // phase 1
    unsigned short* Qb = B1;    // phase 2 (after k_vtrans consumed Vrow)
    unsigned short* J = XI;     // phase 3 (XI/XT dead after QKV GEMMs)

    float* out_img = (float*)d_out;
    float* out_txt = (float*)d_out + 6291456;

    k_cast<<<6144, 256, 0, stream>>>(image, XI, 1572864);
    k_cast<<<1536, 256, 0, stream>>>(text, XT, 393216);

    dim3 tg(48, 48);
    dim3 gi(24, 16);  // M=2048
    dim3 gt(24, 4);   // M=512

    // V first (row-major), then transpose, freeing B1 for Qb
    k_tcast<<<tg, 256, 0, stream>>>(Wv, WT);
    k_gemm<<<gi, 256, 0, stream>>>(XI, WT, bv, Vrow, 512, 0);
    k_tcast<<<tg, 256, 0, stream>>>(Wav, WT);
    k_gemm<<<gt, 256, 0, stream>>>(XT, WT, bav, Vrow, 0, 0);
    k_vtrans<<<dim3(40, 2, 24), 256, 0, stream>>>(Vrow, VT);

    k_tcast<<<tg, 256, 0, stream>>>(Wq, WT);
    k_gemm<<<gi, 256, 0, stream>>>(XI, WT, bq, Qb, 512, 0);
    k_tcast<<<tg, 256, 0, stream>>>(Waq, WT);
    k_gemm<<<gt, 256, 0, stream>>>(XT, WT, baq, Qb, 0, 0);

    k_tcast<<<tg, 256, 0, stream>>>(Wk, WT);
    k_gemm<<<gi, 256, 0, stream>>>(XI, WT, bk, Kbuf, 512, 0);
    k_tcast<<<tg, 256, 0, stream>>>(Wak, WT);
    k_gemm<<<gt, 256, 0, stream>>>(XT, WT, bak, Kbuf, 0, 0);

    k_normrope<<<dim3(640, 24, 2), 256, 0, stream>>>(Qb, Kbuf, gq, gk, gaq, gak,
                                                     img_cos, img_sin, txt_cos, txt_sin);

    k_attn<<<dim3(40, 24), 256, 0, stream>>>(Qb, Kbuf, VT, J);

    k_tcast<<<tg, 256, 0, stream>>>(Wao, WT);
    k_gemm<<<gt, 256, 0, stream>>>(J, WT, bao, out_txt, 0, 2);
    k_tcast<<<tg, 256, 0, stream>>>(Wo, WT);
    k_gemm<<<gi, 256, 0, stream>>>(J + (size_t)512 * 3072, WT, bo, out_img, 0, 2);
}

// Round 9
// 983.853 us; speedup vs baseline: 1.2295x; 1.1157x over previous
//
#include <hip/hip_runtime.h>
#include <stdint.h>

typedef uint32_t u32;
typedef float f32x4 __attribute__((ext_vector_type(4)));
typedef u32 u32x4 __attribute__((ext_vector_type(4)));
typedef short s16x8 __attribute__((ext_vector_type(8)));

#define DI __device__ __forceinline__

DI unsigned short f2bf(float f) {
    u32 u = __builtin_bit_cast(u32, f);
    u32 r = (u + 0x7fffu + ((u >> 16) & 1u)) >> 16;
    return (unsigned short)r;
}
DI float bf2f(unsigned short s) {
    u32 u = ((u32)s) << 16;
    return __builtin_bit_cast(float, u);
}
DI u32 pack2(unsigned short lo, unsigned short hi) { return (u32)lo | ((u32)hi << 16); }

DI void mfma_bf16(f32x4& acc, u32x4 a, u32x4 b) {
    acc = __builtin_amdgcn_mfma_f32_16x16x32_bf16(
        __builtin_bit_cast(s16x8, a), __builtin_bit_cast(s16x8, b), acc, 0, 0, 0);
}

DI void gload16(const unsigned short* g, unsigned short* l) {
    __builtin_amdgcn_global_load_lds(
        (const __attribute__((address_space(1))) uint32_t*)(uintptr_t)g,
        (__attribute__((address_space(3))) uint32_t*)(uint32_t)(uintptr_t)l, 16, 0, 0);
}

// ---------------- cast f32 -> bf16 ----------------
__global__ __launch_bounds__(256) void k_cast(const float* __restrict__ X,
                                              unsigned short* __restrict__ Y, int n4) {
    int i = blockIdx.x * 256 + threadIdx.x;
    if (i < n4) {
        float4 v = ((const float4*)X)[i];
        ushort4 o;
        o.x = f2bf(v.x); o.y = f2bf(v.y); o.z = f2bf(v.z); o.w = f2bf(v.w);
        ((ushort4*)Y)[i] = o;
    }
}

// ---------------- cast+transpose W[K][N] f32 -> Wt[N][K] bf16 ----------------
__global__ __launch_bounds__(256) void k_tcast(const float* __restrict__ W,
                                               unsigned short* __restrict__ Wt) {
    __shared__ float t[64][65];
    const int K = 3072;
    int k0 = blockIdx.y * 64, n0 = blockIdx.x * 64;
    int tid = threadIdx.x;
    int r = tid >> 4, c4 = (tid & 15) * 4;
#pragma unroll
    for (int i = 0; i < 4; i++) {
        float4 v = *(const float4*)(W + (size_t)(k0 + r + i * 16) * K + n0 + c4);
        t[r + i * 16][c4 + 0] = v.x;
        t[r + i * 16][c4 + 1] = v.y;
        t[r + i * 16][c4 + 2] = v.z;
        t[r + i * 16][c4 + 3] = v.w;
    }
    __syncthreads();
#pragma unroll
    for (int i = 0; i < 4; i++) {
        int n = r + i * 16;
        ushort4 o;
        o.x = f2bf(t[c4 + 0][n]);
        o.y = f2bf(t[c4 + 1][n]);
        o.z = f2bf(t[c4 + 2][n]);
        o.w = f2bf(t[c4 + 3][n]);
        *(ushort4*)(Wt + (size_t)(n0 + n) * K + k0 + c4) = o;
    }
}

// ---------------- fused joint-M GEMM, PER-STREAM weights ----------------
// Joint M = 2560. sel = (m0 >= 512): txt rows use Bt0/bias0, img rows Bt1/bias1.
// epi 0: bf16 out0 [24][2560][128] at (h=n>>7, s=m0+m, d=n&127)
// epi 1: bf16 VT out0 [24][128][2560], per-32 kv interleave p = 8*lg + 4*(i&1) + r
// epi 2: f32; s<512 -> out0[s][n] (txt), else out1[s-512][n] (img)
__global__ __launch_bounds__(256) void k_gemm(
    const unsigned short* __restrict__ Atxt, const unsigned short* __restrict__ Aimg,
    const unsigned short* __restrict__ Bt0, const unsigned short* __restrict__ Bt1,
    const float* __restrict__ bias0, const float* __restrict__ bias1,
    void* out0, void* out1, int epi) {
    __shared__ unsigned short Al[2][4096];  // [128 rows][32 k] linear
    __shared__ unsigned short Bl[2][4096];
    const int K = 3072;
    int tid = threadIdx.x;
    int lane = tid & 63, w = tid >> 6;
    int wr = w >> 1, wc = w & 1;
    int l15 = lane & 15, lg = lane >> 4;
    int m0 = blockIdx.y * 128, n0 = blockIdx.x * 128;
    int sel = (int)(m0 >= 512);  // 0 = text stream, 1 = image stream
    const unsigned short* Bt = sel ? Bt1 : Bt0;
    const float* bias = sel ? bias1 : bias0;
    const unsigned short* Abase =
        sel ? (Aimg + (size_t)(m0 - 512) * K) : (Atxt + (size_t)m0 * K);

    f32x4 acc[4][4] = {};

    int srow = w * 32 + (lane >> 2);
    int colsw = ((lane & 3) ^ ((lane >> 3) & 3)) * 8;  // pre-swizzled source granule
    const unsigned short* Ag = Abase + (size_t)srow * K + colsw;
    const unsigned short* Bg = Bt + (size_t)(n0 + srow) * K + colsw;
    int gsw = (l15 >> 1) & 3;  // read-side inverse swizzle

#pragma unroll
    for (int i = 0; i < 2; i++) {
        gload16(Ag + (size_t)i * 16 * K, &Al[0][w * 1024 + i * 512]);
        gload16(Bg + (size_t)i * 16 * K, &Bl[0][w * 1024 + i * 512]);
    }
    __syncthreads();

    int cur = 0;
    for (int k0 = 0; k0 < K; k0 += 32) {
        if (k0 + 32 < K) {
#pragma unroll
            for (int i = 0; i < 2; i++) {
                gload16(Ag + (size_t)i * 16 * K + k0 + 32, &Al[cur ^ 1][w * 1024 + i * 512]);
                gload16(Bg + (size_t)i * 16 * K + k0 + 32, &Bl[cur ^ 1][w * 1024 + i * 512]);
            }
        }
        u32x4 af[4], bf[4];
#pragma unroll
        for (int i = 0; i < 4; i++) {
            int ar = wr * 64 + i * 16 + l15;
            int br = wc * 64 + i * 16 + l15;
            af[i] = *(const u32x4*)&Al[cur][ar * 32 + (lg ^ gsw) * 8];
            bf[i] = *(const u32x4*)&Bl[cur][br * 32 + (lg ^ gsw) * 8];
        }
#pragma unroll
        for (int i = 0; i < 4; i++)
#pragma unroll
            for (int j = 0; j < 4; j++) mfma_bf16(acc[i][j], af[i], bf[j]);
        __syncthreads();
        cur ^= 1;
    }

#pragma unroll
    for (int j = 0; j < 4; j++) {
        int n = n0 + wc * 64 + j * 16 + l15;
        float b = bias[n];
        int h = n >> 7, d = n & 127;
#pragma unroll
        for (int i = 0; i < 4; i++) {
            if (epi == 1) {
                // interleaved-transposed VT write, 4 consecutive positions -> 8B store
                int sb = m0 + wr * 64 + (i >> 1) * 32 + lg * 8 + (i & 1) * 4;
                ushort4 o;
                o.x = f2bf(acc[i][j][0] + b);
                o.y = f2bf(acc[i][j][1] + b);
                o.z = f2bf(acc[i][j][2] + b);
                o.w = f2bf(acc[i][j][3] + b);
                *(ushort4*)((unsigned short*)out0 + ((size_t)h * 128 + d) * 2560 + sb) = o;
            } else {
#pragma unroll
                for (int r = 0; r < 4; r++) {
                    int s = m0 + wr * 64 + i * 16 + lg * 4 + r;
                    float v = acc[i][j][r] + b;
                    if (epi == 2) {
                        float* ob = (s < 512) ? (float*)out0 + (size_t)s * 3072
                                              : (float*)out1 + (size_t)(s - 512) * 3072;
                        ob[n] = v;
                    } else {
                        ((unsigned short*)out0)[((size_t)h * 2560 + s) * 128 + d] = f2bf(v);
                    }
                }
            }
        }
    }
}

// ---------------- RMSNorm + RoPE, in-place on Q and K ----------------
__global__ __launch_bounds__(256) void k_normrope(unsigned short* __restrict__ Q,
                                                  unsigned short* __restrict__ Kb,
                                                  const float* gq, const float* gk,
                                                  const float* gaq, const float* gak,
                                                  const float* img_cos, const float* img_sin,
                                                  const float* txt_cos, const float* txt_sin) {
    int w = threadIdx.x >> 6, lane = threadIdx.x & 63;
    int s = blockIdx.x * 4 + w;
    int h = blockIdx.y;
    int tensor = blockIdx.z;
    unsigned short* base = (tensor ? Kb : Q) + ((size_t)h * 2560 + s) * 128;
    bool txt = s < 512;
    const float* g = tensor ? (txt ? gak : gk) : (txt ? gaq : gq);
    const float* ct = txt ? txt_cos + (size_t)s * 64 : img_cos + (size_t)(s - 512) * 64;
    const float* st = txt ? txt_sin + (size_t)s * 64 : img_sin + (size_t)(s - 512) * 64;

    u32 v = ((u32*)base)[lane];
    float xr = bf2f((unsigned short)(v & 0xffff));
    float xi = bf2f((unsigned short)(v >> 16));
    float ss = xr * xr + xi * xi;
#pragma unroll
    for (int m = 1; m < 64; m <<= 1) ss += __shfl_xor(ss, m);
    float rs = rsqrtf(ss * (1.0f / 128.0f) + 1e-6f);
    float c = ct[lane], sn = st[lane];
    float g0 = g[2 * lane], g1 = g[2 * lane + 1];
    xr *= rs * g0;
    xi *= rs * g1;
    float orr = xr * c - xi * sn;
    float oi = xr * sn + xi * c;
    ((u32*)base)[lane] = pack2(f2bf(orr), f2bf(oi));
}

// ---------------- flash attention, 128 threads (2 waves), 32 q-rows/wg ----------------
// Kl [64][128] granule-swizzled; Vl [128][64] kv-interleaved+swizzled -> PV is 16 b128
__global__ __launch_bounds__(128) void k_attn(const unsigned short* __restrict__ Q,
                                              const unsigned short* __restrict__ Kb,
                                              const unsigned short* __restrict__ Vt,
                                              unsigned short* __restrict__ J) {
    __shared__ unsigned short Kl[64 * 128];
    __shared__ unsigned short Vl[128 * 64];
    int tid = threadIdx.x;
    int lane = tid & 63, w = tid >> 6;  // w in {0,1}
    int l15 = lane & 15, lg = lane >> 4;
    int h = blockIdx.y, qb = blockIdx.x;  // qb in [0,80)
    int q0 = qb * 32 + w * 16;
    const float scale = 0.08838834764831845f;

    u32x4 qf[4];
    const unsigned short* qrow = Q + ((size_t)h * 2560 + q0 + l15) * 128;
#pragma unroll
    for (int c = 0; c < 4; c++) qf[c] = *(const u32x4*)(qrow + c * 32 + lg * 8);

    float m_run = -1e30f, l_run = 0.0f;
    f32x4 oa[8] = {};

    int tr = tid >> 4, tg16 = tid & 15;  // K stage: 8 rows/thread
    const unsigned short* Kg = Kb + (size_t)h * 2560 * 128;
    const unsigned short* Vg = Vt + ((size_t)h * 128 + tid) * 2560;  // d = tid
    int dsw = l15 & 7;

    for (int kt = 0; kt < 40; kt++) {
        __syncthreads();
#pragma unroll
        for (int i = 0; i < 8; i++) {
            int row = tr + i * 8;
            ((u32x4*)Kl)[row * 16 + (tg16 ^ (row & 7))] =
                *(const u32x4*)(Kg + (size_t)(kt * 64 + row) * 128 + tg16 * 8);
        }
#pragma unroll
        for (int g = 0; g < 8; g++)
            ((u32x4*)Vl)[tid * 8 + (g ^ (tid & 7))] = *(const u32x4*)(Vg + kt * 64 + g * 8);
        __syncthreads();

        // S = K * Q^T (swapped): lane owns q-col l15, kv-rows ks*16 + 4lg + r
        f32x4 sc[4] = {};
#pragma unroll
        for (int ks = 0; ks < 4; ks++)
#pragma unroll
            for (int c = 0; c < 4; c++) {
                int row = ks * 16 + l15;
                u32x4 kf = ((const u32x4*)Kl)[row * 16 + ((4 * c + lg) ^ dsw)];
                mfma_bf16(sc[ks], kf, qf[c]);
            }

        float ps[16];
        float tmax = -1e30f;
#pragma unroll
        for (int ks = 0; ks < 4; ks++)
#pragma unroll
            for (int r = 0; r < 4; r++) {
                float sv = sc[ks][r] * scale;
                ps[ks * 4 + r] = sv;
                tmax = fmaxf(tmax, sv);
            }
        tmax = fmaxf(tmax, __shfl_xor(tmax, 16));
        tmax = fmaxf(tmax, __shfl_xor(tmax, 32));
        float m_new = fmaxf(m_run, tmax);
        float fsc = __expf(m_run - m_new);
        float lsum = 0.0f;
#pragma unroll
        for (int t = 0; t < 16; t++) {
            ps[t] = __expf(ps[t] - m_new);
            lsum += ps[t];
        }
        lsum += __shfl_xor(lsum, 16);
        lsum += __shfl_xor(lsum, 32);
        l_run = l_run * fsc + lsum;
        m_run = m_new;
#pragma unroll
        for (int dg = 0; dg < 8; dg++) oa[dg] *= fsc;

        // P -> bf16 frags; slot j of chunk c holds kv = 32c + 16(j>>2) + 4lg + (j&3)
        u32x4 pb[2];
#pragma unroll
        for (int c = 0; c < 2; c++)
#pragma unroll
            for (int i = 0; i < 4; i++)
                pb[c][i] = pack2(f2bf(ps[8 * c + 2 * i]), f2bf(ps[8 * c + 2 * i + 1]));

        // O^T += V^T * P: interleaved layout -> A-frag is ONE b128 per (dg,c)
#pragma unroll
        for (int dg = 0; dg < 8; dg++) {
            int d = dg * 16 + l15;
#pragma unroll
            for (int c = 0; c < 2; c++) {
                u32x4 vf = ((const u32x4*)Vl)[d * 8 + ((4 * c + lg) ^ dsw)];
                mfma_bf16(oa[dg], vf, pb[c]);
            }
        }
    }

    float inv = 1.0f / l_run;
#pragma unroll
    for (int dg = 0; dg < 8; dg++)
#pragma unroll
        for (int r = 0; r < 4; r++) {
            int d = dg * 16 + lg * 4 + r;
            J[(size_t)(q0 + l15) * 3072 + h * 128 + d] = f2bf(oa[dg][r] * inv);
        }
}

extern "C" void kernel_launch(void* const* d_in, const int* in_sizes, int n_in,
                              void* d_out, int out_size, void* d_ws, size_t ws_size,
                              hipStream_t stream) {
    const float* image = (const float*)d_in[0];
    const float* text = (const float*)d_in[1];
    const float* img_cos = (const float*)d_in[2];
    const float* img_sin = (const float*)d_in[3];
    const float* txt_cos = (const float*)d_in[4];
    const float* txt_sin = (const float*)d_in[5];
    const float* Wq = (const float*)d_in[6];
    const float* bq = (const float*)d_in[7];
    const float* Wk = (const float*)d_in[8];
    const float* bk = (const float*)d_in[9];
    const float* Wv = (const float*)d_in[10];
    const float* bv = (const float*)d_in[11];
    const float* Waq = (const float*)d_in[12];
    const float* baq = (const float*)d_in[13];
    const float* Wak = (const float*)d_in[14];
    const float* bak = (const float*)d_in[15];
    const float* Wav = (const float*)d_in[16];
    const float* bav = (const float*)d_in[17];
    const float* gq = (const float*)d_in[18];
    const float* gk = (const float*)d_in[19];
    const float* gaq = (const float*)d_in[20];
    const float* gak = (const float*)d_in[21];
    const float* Wo = (const float*)d_in[22];
    const float* bo = (const float*)d_in[23];
    const float* Wao = (const float*)d_in[24];
    const float* bao = (const float*)d_in[25];

    // Arena A = d_ws (peak 69.2MB < proven 81.8MB):
    //   WT0 [0,18874368)          txt-stream W^T per phase; J after attention
    //   WT1 [18874368,37748736)   img-stream W^T per phase; Wao^T in final phase
    //   Qb  [37748736,53477376)   Q; Wo^T in final phase (spans into dead Kb)
    //   Kb  [53477376,69206016)
    // Arena B = d_out (31457280 B, fully rewritten by final GEMM):
    //   XI [0,12582912)  XT [12582912,15728640)  VT [15728640,31457280)
    char* A = (char*)d_ws;
    char* B = (char*)d_out;
    unsigned short* WT0 = (unsigned short*)A;
    unsigned short* WT1 = (unsigned short*)(A + 18874368);
    unsigned short* Qb = (unsigned short*)(A + 37748736);
    unsigned short* Kbuf = (unsigned short*)(A + 53477376);
    unsigned short* J = WT0;     // after attention (WT slots dead)
    unsigned short* WTao = WT1;  // final phase
    unsigned short* WTo = Qb;    // final phase (Qb/Kb dead)
    unsigned short* XI = (unsigned short*)B;
    unsigned short* XT = (unsigned short*)(B + 12582912);
    unsigned short* VT = (unsigned short*)(B + 15728640);
    float* out_img = (float*)d_out;
    float* out_txt = (float*)d_out + 6291456;

    dim3 tg(48, 48);
    dim3 gj(24, 20, 1);  // joint-M GEMM grid

    k_cast<<<6144, 256, 0, stream>>>(image, XI, 1572864);
    k_cast<<<1536, 256, 0, stream>>>(text, XT, 393216);

    // Q: txt rows use Waq, img rows use Wq
    k_tcast<<<tg, 256, 0, stream>>>(Waq, WT0);
    k_tcast<<<tg, 256, 0, stream>>>(Wq, WT1);
    k_gemm<<<gj, 256, 0, stream>>>(XT, XI, WT0, WT1, baq, bq, Qb, Qb, 0);

    // K
    k_tcast<<<tg, 256, 0, stream>>>(Wak, WT0);
    k_tcast<<<tg, 256, 0, stream>>>(Wk, WT1);
    k_gemm<<<gj, 256, 0, stream>>>(XT, XI, WT0, WT1, bak, bk, Kbuf, Kbuf, 0);

    // V (direct interleaved-transposed epilogue)
    k_tcast<<<tg, 256, 0, stream>>>(Wav, WT0);
    k_tcast<<<tg, 256, 0, stream>>>(Wv, WT1);
    k_gemm<<<gj, 256, 0, stream>>>(XT, XI, WT0, WT1, bav, bv, VT, VT, 1);

    k_normrope<<<dim3(640, 24, 2), 256, 0, stream>>>(Qb, Kbuf, gq, gk, gaq, gak,
                                                     img_cos, img_sin, txt_cos, txt_sin);

    k_attn<<<dim3(80, 24), 128, 0, stream>>>(Qb, Kbuf, VT, J);

    // fused output projections: txt rows -> Wao/bao -> out_txt; img rows -> Wo/bo -> out_img
    k_tcast<<<tg, 256, 0, stream>>>(Wao, WTao);
    k_tcast<<<tg, 256, 0, stream>>>(Wo, WTo);
    k_gemm<<<gj, 256, 0, stream>>>(J, J + (size_t)512 * 3072, WTao, WTo, bao, bo,
                                   out_txt, out_img, 2);
}

// Round 11
// 791.906 us; speedup vs baseline: 1.5275x; 1.2424x over previous
//
#include <hip/hip_runtime.h>
#include <stdint.h>

typedef uint32_t u32;
typedef float f32x4 __attribute__((ext_vector_type(4)));
typedef u32 u32x4 __attribute__((ext_vector_type(4)));
typedef short s16x8 __attribute__((ext_vector_type(8)));

#define DI __device__ __forceinline__

DI unsigned short f2bf(float f) {
    u32 u = __builtin_bit_cast(u32, f);
    u32 r = (u + 0x7fffu + ((u >> 16) & 1u)) >> 16;
    return (unsigned short)r;
}
DI float bf2f(unsigned short s) {
    u32 u = ((u32)s) << 16;
    return __builtin_bit_cast(float, u);
}
DI u32 pack2(unsigned short lo, unsigned short hi) { return (u32)lo | ((u32)hi << 16); }

DI void mfma_bf16(f32x4& acc, u32x4 a, u32x4 b) {
    acc = __builtin_amdgcn_mfma_f32_16x16x32_bf16(
        __builtin_bit_cast(s16x8, a), __builtin_bit_cast(s16x8, b), acc, 0, 0, 0);
}

DI void gload16(const unsigned short* g, unsigned short* l) {
    __builtin_amdgcn_global_load_lds(
        (const __attribute__((address_space(1))) uint32_t*)(uintptr_t)g,
        (__attribute__((address_space(3))) uint32_t*)(uint32_t)(uintptr_t)l, 16, 0, 0);
}

// ---------------- cast f32 -> bf16 ----------------
__global__ __launch_bounds__(256) void k_cast(const float* __restrict__ X,
                                              unsigned short* __restrict__ Y, int n4) {
    int i = blockIdx.x * 256 + threadIdx.x;
    if (i < n4) {
        float4 v = ((const float4*)X)[i];
        ushort4 o;
        o.x = f2bf(v.x); o.y = f2bf(v.y); o.z = f2bf(v.z); o.w = f2bf(v.w);
        ((ushort4*)Y)[i] = o;
    }
}

// ---------------- cast+transpose W[K][N] f32 -> Wt[N][K] bf16 ----------------
__global__ __launch_bounds__(256) void k_tcast(const float* __restrict__ W,
                                               unsigned short* __restrict__ Wt) {
    __shared__ float t[64][65];
    const int K = 3072;
    int k0 = blockIdx.y * 64, n0 = blockIdx.x * 64;
    int tid = threadIdx.x;
    int r = tid >> 4, c4 = (tid & 15) * 4;
#pragma unroll
    for (int i = 0; i < 4; i++) {
        float4 v = *(const float4*)(W + (size_t)(k0 + r + i * 16) * K + n0 + c4);
        t[r + i * 16][c4 + 0] = v.x;
        t[r + i * 16][c4 + 1] = v.y;
        t[r + i * 16][c4 + 2] = v.z;
        t[r + i * 16][c4 + 3] = v.w;
    }
    __syncthreads();
#pragma unroll
    for (int i = 0; i < 4; i++) {
        int n = r + i * 16;
        ushort4 o;
        o.x = f2bf(t[c4 + 0][n]);
        o.y = f2bf(t[c4 + 1][n]);
        o.z = f2bf(t[c4 + 2][n]);
        o.w = f2bf(t[c4 + 3][n]);
        *(ushort4*)(Wt + (size_t)(n0 + n) * K + k0 + c4) = o;
    }
}

// ---------------- fused joint-M GEMM, PER-STREAM weights ----------------
// Joint M = 2560. sel = (m0 >= 512): txt rows use Bt0/bias0, img rows Bt1/bias1.
// epi 0: bf16 out0 [24][2560][128] at (h=n>>7, s=m0+m, d=n&127)
// epi 1: bf16 VT out0 [24][128][2560], per-32 kv interleave
// epi 2: f32; s<512 -> out0[s][n] (txt), else out1[s-512][n] (img)
__global__ __launch_bounds__(256) void k_gemm(
    const unsigned short* __restrict__ Atxt, const unsigned short* __restrict__ Aimg,
    const unsigned short* __restrict__ Bt0, const unsigned short* __restrict__ Bt1,
    const float* __restrict__ bias0, const float* __restrict__ bias1,
    void* out0, void* out1, int epi) {
    __shared__ unsigned short Al[2][4096];  // [128 rows][32 k] linear
    __shared__ unsigned short Bl[2][4096];
    const int K = 3072;
    int tid = threadIdx.x;
    int lane = tid & 63, w = tid >> 6;
    int wr = w >> 1, wc = w & 1;
    int l15 = lane & 15, lg = lane >> 4;
    int m0 = blockIdx.y * 128, n0 = blockIdx.x * 128;
    int sel = (int)(m0 >= 512);  // 0 = text stream, 1 = image stream
    const unsigned short* Bt = sel ? Bt1 : Bt0;
    const float* bias = sel ? bias1 : bias0;
    const unsigned short* Abase =
        sel ? (Aimg + (size_t)(m0 - 512) * K) : (Atxt + (size_t)m0 * K);

    f32x4 acc[4][4] = {};

    int srow = w * 32 + (lane >> 2);
    int colsw = ((lane & 3) ^ ((lane >> 3) & 3)) * 8;  // pre-swizzled source granule
    const unsigned short* Ag = Abase + (size_t)srow * K + colsw;
    const unsigned short* Bg = Bt + (size_t)(n0 + srow) * K + colsw;
    int gsw = (l15 >> 1) & 3;  // read-side inverse swizzle

#pragma unroll
    for (int i = 0; i < 2; i++) {
        gload16(Ag + (size_t)i * 16 * K, &Al[0][w * 1024 + i * 512]);
        gload16(Bg + (size_t)i * 16 * K, &Bl[0][w * 1024 + i * 512]);
    }
    __syncthreads();

    int cur = 0;
    for (int k0 = 0; k0 < K; k0 += 32) {
        if (k0 + 32 < K) {
#pragma unroll
            for (int i = 0; i < 2; i++) {
                gload16(Ag + (size_t)i * 16 * K + k0 + 32, &Al[cur ^ 1][w * 1024 + i * 512]);
                gload16(Bg + (size_t)i * 16 * K + k0 + 32, &Bl[cur ^ 1][w * 1024 + i * 512]);
            }
        }
        u32x4 af[4], bf[4];
#pragma unroll
        for (int i = 0; i < 4; i++) {
            int ar = wr * 64 + i * 16 + l15;
            int br = wc * 64 + i * 16 + l15;
            af[i] = *(const u32x4*)&Al[cur][ar * 32 + (lg ^ gsw) * 8];
            bf[i] = *(const u32x4*)&Bl[cur][br * 32 + (lg ^ gsw) * 8];
        }
#pragma unroll
        for (int i = 0; i < 4; i++)
#pragma unroll
            for (int j = 0; j < 4; j++) mfma_bf16(acc[i][j], af[i], bf[j]);
        __syncthreads();
        cur ^= 1;
    }

#pragma unroll
    for (int j = 0; j < 4; j++) {
        int n = n0 + wc * 64 + j * 16 + l15;
        float b = bias[n];
        int h = n >> 7, d = n & 127;
#pragma unroll
        for (int i = 0; i < 4; i++) {
            if (epi == 1) {
                // interleaved-transposed VT write, 4 consecutive positions -> 8B store
                int sb = m0 + wr * 64 + (i >> 1) * 32 + lg * 8 + (i & 1) * 4;
                ushort4 o;
                o.x = f2bf(acc[i][j][0] + b);
                o.y = f2bf(acc[i][j][1] + b);
                o.z = f2bf(acc[i][j][2] + b);
                o.w = f2bf(acc[i][j][3] + b);
                *(ushort4*)((unsigned short*)out0 + ((size_t)h * 128 + d) * 2560 + sb) = o;
            } else {
#pragma unroll
                for (int r = 0; r < 4; r++) {
                    int s = m0 + wr * 64 + i * 16 + lg * 4 + r;
                    float v = acc[i][j][r] + b;
                    if (epi == 2) {
                        float* ob = (s < 512) ? (float*)out0 + (size_t)s * 3072
                                              : (float*)out1 + (size_t)(s - 512) * 3072;
                        ob[n] = v;
                    } else {
                        ((unsigned short*)out0)[((size_t)h * 2560 + s) * 128 + d] = f2bf(v);
                    }
                }
            }
        }
    }
}

// ---------------- RMSNorm + RoPE, in-place on Q and K ----------------
__global__ __launch_bounds__(256) void k_normrope(unsigned short* __restrict__ Q,
                                                  unsigned short* __restrict__ Kb,
                                                  const float* gq, const float* gk,
                                                  const float* gaq, const float* gak,
                                                  const float* img_cos, const float* img_sin,
                                                  const float* txt_cos, const float* txt_sin) {
    int w = threadIdx.x >> 6, lane = threadIdx.x & 63;
    int s = blockIdx.x * 4 + w;
    int h = blockIdx.y;
    int tensor = blockIdx.z;
    unsigned short* base = (tensor ? Kb : Q) + ((size_t)h * 2560 + s) * 128;
    bool txt = s < 512;
    const float* g = tensor ? (txt ? gak : gk) : (txt ? gaq : gq);
    const float* ct = txt ? txt_cos + (size_t)s * 64 : img_cos + (size_t)(s - 512) * 64;
    const float* st = txt ? txt_sin + (size_t)s * 64 : img_sin + (size_t)(s - 512) * 64;

    u32 v = ((u32*)base)[lane];
    float xr = bf2f((unsigned short)(v & 0xffff));
    float xi = bf2f((unsigned short)(v >> 16));
    float ss = xr * xr + xi * xi;
#pragma unroll
    for (int m = 1; m < 64; m <<= 1) ss += __shfl_xor(ss, m);
    float rs = rsqrtf(ss * (1.0f / 128.0f) + 1e-6f);
    float c = ct[lane], sn = st[lane];
    float g0 = g[2 * lane], g1 = g[2 * lane + 1];
    xr *= rs * g0;
    xi *= rs * g1;
    float orr = xr * c - xi * sn;
    float oi = xr * sn + xi * c;
    ((u32*)base)[lane] = pack2(f2bf(orr), f2bf(oi));
}

// ---------------- flash attention, 256 threads, 64 q-rows/wg, T14 reg-prefetch ----------------
// Kl [64][128] granule-swizzled; Vl [128][64] kv-interleaved+swizzled (PV = 1 b128/frag).
// Per tile: {barrier -> write prefetched regs->LDS -> issue next-tile loads -> barrier ->
//            compute} so global latency hides under QK/softmax/PV.
__global__ __launch_bounds__(256) void k_attn(const unsigned short* __restrict__ Q,
                                              const unsigned short* __restrict__ Kb,
                                              const unsigned short* __restrict__ Vt,
                                              unsigned short* __restrict__ J) {
    __shared__ unsigned short Kl[64 * 128];
    __shared__ unsigned short Vl[128 * 64];
    int tid = threadIdx.x;
    int lane = tid & 63, w = tid >> 6;  // 4 waves
    int l15 = lane & 15, lg = lane >> 4;
    int h = blockIdx.y, qb = blockIdx.x;  // qb in [0,40)
    int q0 = qb * 64 + w * 16;
    const float scale = 0.08838834764831845f;

    u32x4 qf[4];
    const unsigned short* qrow = Q + ((size_t)h * 2560 + q0 + l15) * 128;
#pragma unroll
    for (int c = 0; c < 4; c++) qf[c] = *(const u32x4*)(qrow + c * 32 + lg * 8);

    float m_run = -1e30f, l_run = 0.0f;
    f32x4 oa[8] = {};

    // staging geometry: K rows tr+16i, granule tg16; V d-row vd, granules vh*4+j
    int tr = tid >> 4, tg16 = tid & 15;
    int vd = tid >> 1, vh = tid & 1;
    const unsigned short* Kg = Kb + (size_t)h * 2560 * 128;
    const unsigned short* Vg = Vt + ((size_t)h * 128 + vd) * 2560;
    int dsw = l15 & 7;

    u32x4 kreg[4], vreg[4];
#pragma unroll
    for (int i = 0; i < 4; i++)
        kreg[i] = *(const u32x4*)(Kg + (size_t)(tr + i * 16) * 128 + tg16 * 8);
#pragma unroll
    for (int j = 0; j < 4; j++)
        vreg[j] = *(const u32x4*)(Vg + (vh * 4 + j) * 8);

    for (int kt = 0; kt < 40; kt++) {
        __syncthreads();  // previous compute done reading LDS
#pragma unroll
        for (int i = 0; i < 4; i++) {
            int row = tr + i * 16;
            ((u32x4*)Kl)[row * 16 + (tg16 ^ (row & 7))] = kreg[i];
        }
#pragma unroll
        for (int j = 0; j < 4; j++)
            ((u32x4*)Vl)[vd * 8 + ((vh * 4 + j) ^ (vd & 7))] = vreg[j];
        if (kt + 1 < 40) {  // issue next-tile loads; in flight during compute
#pragma unroll
            for (int i = 0; i < 4; i++)
                kreg[i] = *(const u32x4*)(Kg + (size_t)((kt + 1) * 64 + tr + i * 16) * 128 +
                                          tg16 * 8);
#pragma unroll
            for (int j = 0; j < 4; j++)
                vreg[j] = *(const u32x4*)(Vg + (kt + 1) * 64 + (vh * 4 + j) * 8);
        }
        __syncthreads();  // LDS writes visible

        // S = K * Q^T (swapped): lane owns q-col l15, kv-rows ks*16 + 4lg + r
        f32x4 sc[4] = {};
        __builtin_amdgcn_s_setprio(1);
#pragma unroll
        for (int ks = 0; ks < 4; ks++)
#pragma unroll
            for (int c = 0; c < 4; c++) {
                int row = ks * 16 + l15;
                u32x4 kf = ((const u32x4*)Kl)[row * 16 + ((4 * c + lg) ^ dsw)];
                mfma_bf16(sc[ks], kf, qf[c]);
            }
        __builtin_amdgcn_s_setprio(0);

        float ps[16];
        float tmax = -1e30f;
#pragma unroll
        for (int ks = 0; ks < 4; ks++)
#pragma unroll
            for (int r = 0; r < 4; r++) {
                float sv = sc[ks][r] * scale;
                ps[ks * 4 + r] = sv;
                tmax = fmaxf(tmax, sv);
            }
        tmax = fmaxf(tmax, __shfl_xor(tmax, 16));
        tmax = fmaxf(tmax, __shfl_xor(tmax, 32));
        float m_new = fmaxf(m_run, tmax);
        float fsc = __expf(m_run - m_new);
        float lsum = 0.0f;
#pragma unroll
        for (int t = 0; t < 16; t++) {
            ps[t] = __expf(ps[t] - m_new);
            lsum += ps[t];
        }
        lsum += __shfl_xor(lsum, 16);
        lsum += __shfl_xor(lsum, 32);
        l_run = l_run * fsc + lsum;
        m_run = m_new;
#pragma unroll
        for (int dg = 0; dg < 8; dg++) oa[dg] *= fsc;

        // P -> bf16 frags; slot j of chunk c holds kv = 32c + 16(j>>2) + 4lg + (j&3)
        u32x4 pb[2];
#pragma unroll
        for (int c = 0; c < 2; c++)
#pragma unroll
            for (int i = 0; i < 4; i++)
                pb[c][i] = pack2(f2bf(ps[8 * c + 2 * i]), f2bf(ps[8 * c + 2 * i + 1]));

        // O^T += V^T * P: interleaved layout -> A-frag is ONE b128 per (dg,c)
        __builtin_amdgcn_s_setprio(1);
#pragma unroll
        for (int dg = 0; dg < 8; dg++) {
            int d = dg * 16 + l15;
#pragma unroll
            for (int c = 0; c < 2; c++) {
                u32x4 vf = ((const u32x4*)Vl)[d * 8 + ((4 * c + lg) ^ dsw)];
                mfma_bf16(oa[dg], vf, pb[c]);
            }
        }
        __builtin_amdgcn_s_setprio(0);
    }

    float inv = 1.0f / l_run;
#pragma unroll
    for (int dg = 0; dg < 8; dg++)
#pragma unroll
        for (int r = 0; r < 4; r++) {
            int d = dg * 16 + lg * 4 + r;
            J[(size_t)(q0 + l15) * 3072 + h * 128 + d] = f2bf(oa[dg][r] * inv);
        }
}

extern "C" void kernel_launch(void* const* d_in, const int* in_sizes, int n_in,
                              void* d_out, int out_size, void* d_ws, size_t ws_size,
                              hipStream_t stream) {
    const float* image = (const float*)d_in[0];
    const float* text = (const float*)d_in[1];
    const float* img_cos = (const float*)d_in[2];
    const float* img_sin = (const float*)d_in[3];
    const float* txt_cos = (const float*)d_in[4];
    const float* txt_sin = (const float*)d_in[5];
    const float* Wq = (const float*)d_in[6];
    const float* bq = (const float*)d_in[7];
    const float* Wk = (const float*)d_in[8];
    const float* bk = (const float*)d_in[9];
    const float* Wv = (const float*)d_in[10];
    const float* bv = (const float*)d_in[11];
    const float* Waq = (const float*)d_in[12];
    const float* baq = (const float*)d_in[13];
    const float* Wak = (const float*)d_in[14];
    const float* bak = (const float*)d_in[15];
    const float* Wav = (const float*)d_in[16];
    const float* bav = (const float*)d_in[17];
    const float* gq = (const float*)d_in[18];
    const float* gk = (const float*)d_in[19];
    const float* gaq = (const float*)d_in[20];
    const float* gak = (const float*)d_in[21];
    const float* Wo = (const float*)d_in[22];
    const float* bo = (const float*)d_in[23];
    const float* Wao = (const float*)d_in[24];
    const float* bao = (const float*)d_in[25];

    // Arena A = d_ws (peak 69.2MB < proven 81.8MB):
    //   WT0 [0,18874368)          txt-stream W^T per phase; J after attention
    //   WT1 [18874368,37748736)   img-stream W^T per phase; Wao^T in final phase
    //   Qb  [37748736,53477376)   Q; Wo^T in final phase (spans into dead Kb)
    //   Kb  [53477376,69206016)
    // Arena B = d_out (31457280 B, fully rewritten by final GEMM):
    //   XI [0,12582912)  XT [12582912,15728640)  VT [15728640,31457280)
    char* A = (char*)d_ws;
    char* B = (char*)d_out;
    unsigned short* WT0 = (unsigned short*)A;
    unsigned short* WT1 = (unsigned short*)(A + 18874368);
    unsigned short* Qb = (unsigned short*)(A + 37748736);
    unsigned short* Kbuf = (unsigned short*)(A + 53477376);
    unsigned short* J = WT0;     // after attention (WT slots dead)
    unsigned short* WTao = WT1;  // final phase
    unsigned short* WTo = Qb;    // final phase (Qb/Kb dead)
    unsigned short* XI = (unsigned short*)B;
    unsigned short* XT = (unsigned short*)(B + 12582912);
    unsigned short* VT = (unsigned short*)(B + 15728640);
    float* out_img = (float*)d_out;
    float* out_txt = (float*)d_out + 6291456;

    dim3 tg(48, 48);
    dim3 gj(24, 20, 1);  // joint-M GEMM grid

    k_cast<<<6144, 256, 0, stream>>>(image, XI, 1572864);
    k_cast<<<1536, 256, 0, stream>>>(text, XT, 393216);

    // Q: txt rows use Waq, img rows use Wq
    k_tcast<<<tg, 256, 0, stream>>>(Waq, WT0);
    k_tcast<<<tg, 256, 0, stream>>>(Wq, WT1);
    k_gemm<<<gj, 256, 0, stream>>>(XT, XI, WT0, WT1, baq, bq, Qb, Qb, 0);

    // K
    k_tcast<<<tg, 256, 0, stream>>>(Wak, WT0);
    k_tcast<<<tg, 256, 0, stream>>>(Wk, WT1);
    k_gemm<<<gj, 256, 0, stream>>>(XT, XI, WT0, WT1, bak, bk, Kbuf, Kbuf, 0);

    // V (direct interleaved-transposed epilogue)
    k_tcast<<<tg, 256, 0, stream>>>(Wav, WT0);
    k_tcast<<<tg, 256, 0, stream>>>(Wv, WT1);
    k_gemm<<<gj, 256, 0, stream>>>(XT, XI, WT0, WT1, bav, bv, VT, VT, 1);

    k_normrope<<<dim3(640, 24, 2), 256, 0, stream>>>(Qb, Kbuf, gq, gk, gaq, gak,
                                                     img_cos, img_sin, txt_cos, txt_sin);

    k_attn<<<dim3(40, 24), 256, 0, stream>>>(Qb, Kbuf, VT, J);

    // fused output projections: txt rows -> Wao/bao -> out_txt; img rows -> Wo/bo -> out_img
    k_tcast<<<tg, 256, 0, stream>>>(Wao, WTao);
    k_tcast<<<tg, 256, 0, stream>>>(Wo, WTo);
    k_gemm<<<gj, 256, 0, stream>>>(J, J + (size_t)512 * 3072, WTao, WTo, bao, bo,
                                   out_txt, out_img, 2);
}